// Round 6
// baseline (63.360 us; speedup 1.0000x reference)
//
#include <hip/hip_runtime.h>
#include <hip/hip_bf16.h>

// VQ-VAE vector quantizer, MI355X — 2-dispatch fused design.
// [k_prep]  64 blocks: emb -> swizzled fp8 E (x512) + cn=||e||^2 fp32; loss=0
// [k_fused] 1024 blocks (4/CU): block owns 32 hw rows of one b.
//   A: transpose lat->swz fp8 A in LDS (never global) + sum(x^2) partial
//   B: 8 E-tiles (16KB) double-buffered via global_load_lds, fp8 MFMA,
//      fp32 fold s = cn - (2/512)t, running argmin in regs
//   C: 4-wave merge, gather q=emb[k*] fp32 -> [B,D,H,W], loss atomicAdd

typedef __attribute__((ext_vector_type(4))) float f32x4;

// workspace layout (bytes)
#define WS_E 0u          // fp8 swz [1024][128] = 131072
#define WS_C 131072u     // f32 cn[1024]        = 4096

#define LOSS_SCALE (1.25f / 4194304.0f)
#define NEG2_INV_LAMBDA (-2.0f / 512.0f)

static __device__ inline unsigned cvt4_fp8(float a, float b, float c, float d) {
    int v = __builtin_amdgcn_cvt_pk_fp8_f32(a, b, 0, false);
    v = __builtin_amdgcn_cvt_pk_fp8_f32(c, d, v, true);
    return (unsigned)v;
}

static __device__ inline void gload_lds16(const void* g, void* l) {
    __builtin_amdgcn_global_load_lds(
        (const __attribute__((address_space(1))) unsigned int*)g,
        (__attribute__((address_space(3))) unsigned int*)l, 16, 0, 0);
}

// ---------------- codebook prep ----------------
__global__ __launch_bounds__(256) void k_prep(const float* __restrict__ emb,
                                              char* __restrict__ Eb,
                                              float* __restrict__ cn,
                                              float* __restrict__ loss) {
    const int t = threadIdx.x;
    const int row = (blockIdx.x << 4) + (t >> 4), c = t & 15;
    const float4* ep = (const float4*)(emb + ((size_t)row << 7) + (c << 3));
    float4 e0 = ep[0], e1 = ep[1];
    float s = e0.x*e0.x + e0.y*e0.y + e0.z*e0.z + e0.w*e0.w
            + e1.x*e1.x + e1.y*e1.y + e1.z*e1.z + e1.w*e1.w;
#pragma unroll
    for (int m = 1; m < 16; m <<= 1) s += __shfl_xor(s, m);
    if (c == 0) cn[row] = s;
    uint2 v;
    v.x = cvt4_fp8(512.f*e0.x, 512.f*e0.y, 512.f*e0.z, 512.f*e0.w);
    v.y = cvt4_fp8(512.f*e1.x, 512.f*e1.y, 512.f*e1.z, 512.f*e1.w);
    *(uint2*)(Eb + row * 128 + ((c * 8) ^ ((row & 7) << 4))) = v;
    if (blockIdx.x == 0 && t == 0) loss[0] = 0.f;
}

// ---------------- fused trans + score + out ----------------
// LDS: A[4096] | ebuf0 @4096 (16K, phase-A Tf overlay) | ebuf1 @20480 (16K) |
//      cs @36864 | ci @37376 | win @37888 | rs @38016  -> 38032 B, 4 blocks/CU.
__global__ __launch_bounds__(256, 4) void k_fused(const float* __restrict__ lat,
                                                  const float* __restrict__ emb,
                                                  const char* __restrict__ Eb,
                                                  const float* __restrict__ cn,
                                                  float* __restrict__ outq,
                                                  float* __restrict__ loss) {
    __shared__ char lds[38048];
    char*  ldsA = lds;                       // 32 rows * 128 B fp8, swizzled
    float* Tf   = (float*)(lds + 4096);      // [128 d][32 hw] fp32, col-swizzled
    float* cs   = (float*)(lds + 36864);
    int*   ci   = (int*)  (lds + 37376);
    int*   win  = (int*)  (lds + 37888);
    float* rs   = (float*)(lds + 38016);

    const int t = threadIdx.x, bm = blockIdx.x;
    const int lane = t & 63, wid = t >> 6;
    const int l15 = lane & 15, lg = lane >> 4;
    const int b = bm >> 5, hw0 = (bm & 31) << 5;

    // ---- issue tile-0 stage into ebuf1 (latency hides under phase A) ----
#pragma unroll
    for (int i = 0; i < 4; ++i) {
        int base = i * 4096 + (wid << 10);
        gload_lds16(Eb + base + lane * 16, lds + 20480 + base);
    }

    // ---- phase A: transpose own rows, fp8-cvt into LDS A, sum(x^2) ----
    const float* latp = lat + ((size_t)b << 17) + hw0;
    float rn = 0.f;
#pragma unroll
    for (int i = 0; i < 4; ++i) {
        int idx = i * 256 + t;
        int d = idx >> 3, hw4 = (idx & 7) << 2;
        float4 v = *(const float4*)(latp + ((size_t)d << 10) + hw4);
        rn = fmaf(v.x, v.x, fmaf(v.y, v.y, fmaf(v.z, v.z, fmaf(v.w, v.w, rn))));
        *(float4*)(&Tf[(d << 5) + (hw4 ^ (((d >> 3) & 7) << 2))]) = v;
    }
#pragma unroll
    for (int m = 1; m < 64; m <<= 1) rn += __shfl_xor(rn, m);
    if (lane == 0) rs[wid] = rn;
    __syncthreads();
    {
        const int rowl = t & 31, c8 = t >> 5;
        float q[16];
#pragma unroll
        for (int j = 0; j < 16; ++j) {
            int d = c8 * 16 + j;
            q[j] = Tf[(d << 5) + (rowl ^ (((d >> 3) & 7) << 2))];
        }
        uint4 w;
        w.x = cvt4_fp8(q[0], q[1], q[2], q[3]);
        w.y = cvt4_fp8(q[4], q[5], q[6], q[7]);
        w.z = cvt4_fp8(q[8], q[9], q[10], q[11]);
        w.w = cvt4_fp8(q[12], q[13], q[14], q[15]);
        *(uint4*)(ldsA + rowl * 128 + ((c8 * 16) ^ ((rowl & 7) << 4))) = w;
    }
    __syncthreads();   // A ready; Tf dead; tile-0 stage drained

    // ---- phase B: 8 E-tiles, double-buffered, fp8 MFMA + running argmin ----
    long av[2][4];
#pragma unroll
    for (int m = 0; m < 2; ++m)
#pragma unroll
        for (int ks = 0; ks < 4; ++ks) {
            int r = m * 16 + l15;
            av[m][ks] = *(const long*)(ldsA + r * 128 +
                        ((ks * 32 + lg * 8) ^ ((r & 7) << 4)));
        }

    float run_s[2][4]; int run_i[2][4];
#pragma unroll
    for (int m = 0; m < 2; ++m)
#pragma unroll
        for (int r = 0; r < 4; ++r) { run_s[m][r] = 3.0e38f; run_i[m][r] = 0; }

    for (int ct = 0; ct < 8; ++ct) {
        char* cur   = lds + (4096 + (((ct & 1) ^ 1) << 14));
        char* other = lds + (4096 + ((ct & 1) << 14));
        if (ct < 7) {                         // stage next tile (overlaps MFMA)
            const char* Eg = Eb + ((size_t)(ct + 1) << 14);
#pragma unroll
            for (int i = 0; i < 4; ++i) {
                int base = i * 4096 + (wid << 10);
                gload_lds16(Eg + base + lane * 16, other + base);
            }
        }
        float cnv[2];
#pragma unroll
        for (int c = 0; c < 2; ++c)
            cnv[c] = cn[(ct << 7) + (wid << 5) + (c << 4) + l15];

        f32x4 acc[2][2];
#pragma unroll
        for (int m = 0; m < 2; ++m)
#pragma unroll
            for (int c = 0; c < 2; ++c) acc[m][c] = (f32x4){0.f, 0.f, 0.f, 0.f};
#pragma unroll
        for (int ks = 0; ks < 4; ++ks) {
            long bv[2];
#pragma unroll
            for (int c = 0; c < 2; ++c) {
                int rr = (wid << 5) + (c << 4) + l15;
                bv[c] = *(const long*)(cur + rr * 128 +
                         ((ks * 32 + lg * 8) ^ ((rr & 7) << 4)));
            }
#pragma unroll
            for (int m = 0; m < 2; ++m)
#pragma unroll
                for (int c = 0; c < 2; ++c)
                    acc[m][c] = __builtin_amdgcn_mfma_f32_16x16x32_fp8_fp8(av[m][ks], bv[c], acc[m][c], 0, 0, 0);
        }
#pragma unroll
        for (int c = 0; c < 2; ++c) {
            int kg = (ct << 7) + (wid << 5) + (c << 4) + l15;
#pragma unroll
            for (int m = 0; m < 2; ++m)
#pragma unroll
                for (int r = 0; r < 4; ++r) {
                    float s = fmaf(NEG2_INV_LAMBDA, acc[m][c][r], cnv[c]);
                    if (s < run_s[m][r]) { run_s[m][r] = s; run_i[m][r] = kg; }
                }
        }
        __syncthreads();                      // tile consumed; next stage drained
    }

    // ---- phase C: merge, gather, store, loss ----
#pragma unroll
    for (int m = 0; m < 2; ++m)
#pragma unroll
        for (int r = 0; r < 4; ++r) {
            float s = run_s[m][r]; int bi = run_i[m][r];
#pragma unroll
            for (int mask = 1; mask < 16; mask <<= 1) {
                float os = __shfl_xor(s, mask);
                int   oi = __shfl_xor(bi, mask);
                if (os < s || (os == s && oi < bi)) { s = os; bi = oi; }
            }
            if (l15 == 0) {
                int row = m * 16 + lg * 4 + r;       // 0..31
                cs[(wid << 5) + row] = s;
                ci[(wid << 5) + row] = bi;
            }
        }
    __syncthreads();
    if (wid == 0) {
        float bs = 0.f;
        if (lane < 32) {
            bs = cs[lane]; int bi = ci[lane];
#pragma unroll
            for (int w = 1; w < 4; ++w) {
                float s2 = cs[(w << 5) + lane]; int i2 = ci[(w << 5) + lane];
                if (s2 < bs || (s2 == bs && i2 < bi)) { bs = s2; bi = i2; }
            }
            win[lane] = bi;
        }
#pragma unroll
        for (int m = 1; m < 64; m <<= 1) bs += __shfl_xor(bs, m);
        if (lane == 0)
            atomicAdd(loss, (bs + rs[0] + rs[1] + rs[2] + rs[3]) * LOSS_SCALE);
    }
    __syncthreads();
    {
        const int rowl = t & 31, dg = t >> 5;        // 8 dgrps x 16 d
        const int bi = win[rowl];
        const float4* eg = (const float4*)(emb + ((size_t)bi << 7) + (dg << 4));
        float* ob = outq + ((size_t)b << 17) + ((size_t)(dg << 4) << 10) + hw0 + rowl;
#pragma unroll
        for (int jj = 0; jj < 4; ++jj) {
            float4 v = eg[jj];
            ob[(size_t)(jj * 4 + 0) << 10] = v.x;
            ob[(size_t)(jj * 4 + 1) << 10] = v.y;
            ob[(size_t)(jj * 4 + 2) << 10] = v.z;
            ob[(size_t)(jj * 4 + 3) << 10] = v.w;
        }
    }
}

extern "C" void kernel_launch(void* const* d_in, const int* in_sizes, int n_in,
                              void* d_out, int out_size, void* d_ws, size_t ws_size,
                              hipStream_t stream) {
    const float* lat = (const float*)d_in[0];   // [32,128,32,32]
    const float* emb = (const float*)d_in[1];   // [1024,128]
    float* out = (float*)d_out;                 // q (4194304) + vq_loss (1)
    char* ws = (char*)d_ws;
    char*  E    = ws + WS_E;
    float* cn   = (float*)(ws + WS_C);
    float* loss = out + 4194304;

    k_prep <<<64,   256, 0, stream>>>(emb, E, cn, loss);
    k_fused<<<1024, 256, 0, stream>>>(lat, emb, E, cn, out, loss);
}

// Round 7
// 33.453 us; speedup vs baseline: 1.8940x; 1.8940x over previous
//
#include <hip/hip_runtime.h>
#include <hip/hip_bf16.h>

// VQ-VAE vector quantizer, MI355X — 2-dispatch, fat-M fused design.
// [k_prep]  64 blocks: emb -> swizzled fp8 E (x512) + cn=||e||^2 fp32; loss=0
// [k_fused] 512 blocks x 256thr (2/CU): block owns 64 hw rows of one b.
//   A: 2 rounds transpose lat -> swz fp8 A in LDS (8KB) + sum(x^2)
//   B: 8 E-tiles (16KB) double-buffered global_load_lds, fp8 MFMA
//      (32/wave/iter), fp32 fold s = cn - (2/512)t, in-wave running argmin
//      (each wave owns 16 rows exclusively -> no cross-wave merge)
//   C: gather q=emb[k*] fp32 -> [B,D,H,W], one loss atomicAdd per block

typedef __attribute__((ext_vector_type(4))) float f32x4;

// workspace layout (bytes)
#define WS_E 0u          // fp8 swz [1024][128] = 131072
#define WS_C 131072u     // f32 cn[1024]        = 4096

#define LOSS_SCALE (1.25f / 4194304.0f)
#define NEG2_INV_LAMBDA (-2.0f / 512.0f)

static __device__ inline unsigned cvt4_fp8(float a, float b, float c, float d) {
    int v = __builtin_amdgcn_cvt_pk_fp8_f32(a, b, 0, false);
    v = __builtin_amdgcn_cvt_pk_fp8_f32(c, d, v, true);
    return (unsigned)v;
}

static __device__ inline void gload_lds16(const void* g, void* l) {
    __builtin_amdgcn_global_load_lds(
        (const __attribute__((address_space(1))) unsigned int*)g,
        (__attribute__((address_space(3))) unsigned int*)l, 16, 0, 0);
}

// ---------------- codebook prep ----------------
__global__ __launch_bounds__(256) void k_prep(const float* __restrict__ emb,
                                              char* __restrict__ Eb,
                                              float* __restrict__ cn,
                                              float* __restrict__ loss) {
    const int t = threadIdx.x;
    const int row = (blockIdx.x << 4) + (t >> 4), c = t & 15;
    const float4* ep = (const float4*)(emb + ((size_t)row << 7) + (c << 3));
    float4 e0 = ep[0], e1 = ep[1];
    float s = e0.x*e0.x + e0.y*e0.y + e0.z*e0.z + e0.w*e0.w
            + e1.x*e1.x + e1.y*e1.y + e1.z*e1.z + e1.w*e1.w;
#pragma unroll
    for (int m = 1; m < 16; m <<= 1) s += __shfl_xor(s, m);
    if (c == 0) cn[row] = s;
    uint2 v;
    v.x = cvt4_fp8(512.f*e0.x, 512.f*e0.y, 512.f*e0.z, 512.f*e0.w);
    v.y = cvt4_fp8(512.f*e1.x, 512.f*e1.y, 512.f*e1.z, 512.f*e1.w);
    *(uint2*)(Eb + row * 128 + ((c * 8) ^ ((row & 7) << 4))) = v;
    if (blockIdx.x == 0 && t == 0) loss[0] = 0.f;
}

// ---------------- fused trans + score + out ----------------
// LDS: A @0 (8K) | ebuf0 @8192 (16K) | ebuf1 @24576 (16K, Tf overlay) |
//      win @40960 (256B) | rs @41216 (32B)  -> 41248 B, 2 blocks/CU (grid 512).
__global__ __launch_bounds__(256, 2) void k_fused(const float* __restrict__ lat,
                                                  const float* __restrict__ emb,
                                                  const char* __restrict__ Eb,
                                                  const float* __restrict__ cn,
                                                  float* __restrict__ outq,
                                                  float* __restrict__ loss) {
    __shared__ char lds[41248];
    char*  ldsA = lds;                       // 64 rows * 128 B fp8, swizzled
    float* Tf   = (float*)(lds + 24576);     // [128 d][32 hw] fp32, col-swizzled
    int*   win  = (int*)  (lds + 40960);
    float* rs   = (float*)(lds + 41216);

    const int t = threadIdx.x, bm = blockIdx.x;
    const int lane = t & 63, wid = t >> 6;
    const int l15 = lane & 15, lg = lane >> 4;
    const int b = bm >> 4, hw0 = (bm & 15) << 6;

    // ---- issue tile-0 stage into ebuf0 (latency hides under phase A) ----
#pragma unroll
    for (int i = 0; i < 4; ++i) {
        int base = (wid << 12) + (i << 10);
        gload_lds16(Eb + base + lane * 16, lds + 8192 + base);
    }

    // ---- phase A: 2 rounds of 32-row transpose -> fp8 A in LDS ----
    const float* latp = lat + ((size_t)b << 17) + hw0;
    float rn = 0.f;
#pragma unroll
    for (int j = 0; j < 2; ++j) {
#pragma unroll
        for (int i = 0; i < 4; ++i) {
            int idx = i * 256 + t;
            int d = idx >> 3, hw4 = (idx & 7) << 2;
            float4 v = *(const float4*)(latp + ((size_t)d << 10) + j * 32 + hw4);
            rn = fmaf(v.x, v.x, fmaf(v.y, v.y, fmaf(v.z, v.z, fmaf(v.w, v.w, rn))));
            *(float4*)(&Tf[(d << 5) + (hw4 ^ (((d >> 3) & 7) << 2))]) = v;
        }
        __syncthreads();
        {
            const int rowl = t & 31, c8 = t >> 5;
            float q[16];
#pragma unroll
            for (int jj = 0; jj < 16; ++jj) {
                int d = c8 * 16 + jj;
                q[jj] = Tf[(d << 5) + (rowl ^ (((d >> 3) & 7) << 2))];
            }
            uint4 w;
            w.x = cvt4_fp8(q[0], q[1], q[2], q[3]);
            w.y = cvt4_fp8(q[4], q[5], q[6], q[7]);
            w.z = cvt4_fp8(q[8], q[9], q[10], q[11]);
            w.w = cvt4_fp8(q[12], q[13], q[14], q[15]);
            int row = j * 32 + rowl;
            *(uint4*)(ldsA + row * 128 + ((c8 * 16) ^ ((row & 7) << 4))) = w;
        }
        __syncthreads();
    }
#pragma unroll
    for (int m = 1; m < 64; m <<= 1) rn += __shfl_xor(rn, m);
    if (lane == 0) rs[4 + wid] = rn;

    // ---- phase B: 8 E-tiles dbuf; wave owns rows [wid*16,+16) ----
    long av[4];
#pragma unroll
    for (int ks = 0; ks < 4; ++ks) {
        int r = (wid << 4) + l15;
        av[ks] = *(const long*)(ldsA + r * 128 + ((ks * 32 + lg * 8) ^ ((r & 7) << 4)));
    }

    float run_s[4]; int run_i[4];
#pragma unroll
    for (int r = 0; r < 4; ++r) { run_s[r] = 3.0e38f; run_i[r] = 0; }

    for (int ct = 0; ct < 8; ++ct) {
        char* cur = lds + 8192 + ((ct & 1) << 14);
        char* oth = lds + 8192 + (((ct & 1) ^ 1) << 14);
        if (ct < 7) {                         // stage next tile (overlaps MFMA)
            const char* Eg = Eb + ((size_t)(ct + 1) << 14);
#pragma unroll
            for (int i = 0; i < 4; ++i) {
                int base = (wid << 12) + (i << 10);
                gload_lds16(Eg + base + lane * 16, oth + base);
            }
        }
        float cnv[8];
#pragma unroll
        for (int c = 0; c < 8; ++c) cnv[c] = cn[(ct << 7) + (c << 4) + l15];

        f32x4 acc[8];
#pragma unroll
        for (int c = 0; c < 8; ++c) acc[c] = (f32x4){0.f, 0.f, 0.f, 0.f};
#pragma unroll
        for (int ks = 0; ks < 4; ++ks) {
            long bv[8];
#pragma unroll
            for (int c = 0; c < 8; ++c) {
                int rr = (c << 4) + l15;
                bv[c] = *(const long*)(cur + rr * 128 +
                         ((ks * 32 + lg * 8) ^ ((rr & 7) << 4)));
            }
#pragma unroll
            for (int c = 0; c < 8; ++c)
                acc[c] = __builtin_amdgcn_mfma_f32_16x16x32_fp8_fp8(av[ks], bv[c], acc[c], 0, 0, 0);
        }
#pragma unroll
        for (int c = 0; c < 8; ++c) {
            int kg = (ct << 7) + (c << 4) + l15;
#pragma unroll
            for (int r = 0; r < 4; ++r) {
                float s = fmaf(NEG2_INV_LAMBDA, acc[c][r], cnv[c]);
                if (s < run_s[r]) { run_s[r] = s; run_i[r] = kg; }
            }
        }
        __syncthreads();                      // tile consumed; next stage drained
    }

    // ---- phase C: in-wave butterfly, win/loss, gather ----
    float bs = 0.f;
#pragma unroll
    for (int r = 0; r < 4; ++r) {
        float s = run_s[r]; int bi = run_i[r];
#pragma unroll
        for (int mask = 1; mask < 16; mask <<= 1) {
            float os = __shfl_xor(s, mask);
            int   oi = __shfl_xor(bi, mask);
            if (os < s || (os == s && oi < bi)) { s = os; bi = oi; }
        }
        if (l15 == 0) {
            win[(wid << 4) + (lg << 2) + r] = bi;
            bs += s;
        }
    }
    {
        float v = (l15 == 0) ? bs : 0.f;
#pragma unroll
        for (int m = 1; m < 64; m <<= 1) v += __shfl_xor(v, m);
        if (lane == 0) rs[wid] = v;
    }
    __syncthreads();
    if (t == 0)
        atomicAdd(loss, (rs[0] + rs[1] + rs[2] + rs[3] +
                         rs[4] + rs[5] + rs[6] + rs[7]) * LOSS_SCALE);
    {
        const int rowl = t & 63, dg = t >> 6;        // 4 dgrps x 32 d
        const int bi = win[rowl];
        const float4* eg = (const float4*)(emb + ((size_t)bi << 7) + (dg << 5));
        float* ob = outq + ((size_t)b << 17) + ((size_t)(dg << 5) << 10) + hw0 + rowl;
#pragma unroll
        for (int jj = 0; jj < 8; ++jj) {
            float4 v = eg[jj];
            ob[(size_t)(jj * 4 + 0) << 10] = v.x;
            ob[(size_t)(jj * 4 + 1) << 10] = v.y;
            ob[(size_t)(jj * 4 + 2) << 10] = v.z;
            ob[(size_t)(jj * 4 + 3) << 10] = v.w;
        }
    }
}

extern "C" void kernel_launch(void* const* d_in, const int* in_sizes, int n_in,
                              void* d_out, int out_size, void* d_ws, size_t ws_size,
                              hipStream_t stream) {
    const float* lat = (const float*)d_in[0];   // [32,128,32,32]
    const float* emb = (const float*)d_in[1];   // [1024,128]
    float* out = (float*)d_out;                 // q (4194304) + vq_loss (1)
    char* ws = (char*)d_ws;
    char*  E    = ws + WS_E;
    float* cn   = (float*)(ws + WS_C);
    float* loss = out + 4194304;

    k_prep <<<64,  256, 0, stream>>>(emb, E, cn, loss);
    k_fused<<<512, 256, 0, stream>>>(lat, emb, E, cn, out, loss);
}

// Round 8
// 30.764 us; speedup vs baseline: 2.0596x; 1.0874x over previous
//
#include <hip/hip_runtime.h>
#include <hip/hip_bf16.h>

// VQ-VAE vector quantizer, MI355X — E-resident single-pass design.
// [k_prep]  64 blocks: emb -> swizzled fp8 E (x512) + cn=||e||^2 fp32; loss=0
// [k_fused] 256 blocks x 512thr (1/CU, 8 waves): block owns 128 hw rows of one b.
//   - stage ENTIRE fp8 E image (128KB) into LDS once (global_load_lds w16)
//   - A-frags direct from lat: lane reads 32 strided fp32 (sibling waves tile
//     each 512B line fully), cvt to fp8 in regs; row-norms in the same pass
//   - phase B barrier-free: wave owns 16 rows, sweeps 1024 codes from LDS,
//     fp32 fold s = cn - (2/512)t, in-wave running argmin
//   - in-wave butterfly, gather q=emb[k*] fp32 -> [B,D,H,W], 1 loss atomic/block
//   2 barriers total.

typedef __attribute__((ext_vector_type(4))) float f32x4;

// workspace layout (bytes)
#define WS_E 0u          // fp8 swz [1024][128] = 131072
#define WS_C 131072u     // f32 cn[1024]        = 4096

#define LOSS_SCALE (1.25f / 4194304.0f)
#define NEG2_INV_LAMBDA (-2.0f / 512.0f)

static __device__ inline unsigned cvt4_fp8(float a, float b, float c, float d) {
    int v = __builtin_amdgcn_cvt_pk_fp8_f32(a, b, 0, false);
    v = __builtin_amdgcn_cvt_pk_fp8_f32(c, d, v, true);
    return (unsigned)v;
}

static __device__ inline void gload_lds16(const void* g, void* l) {
    __builtin_amdgcn_global_load_lds(
        (const __attribute__((address_space(1))) unsigned int*)g,
        (__attribute__((address_space(3))) unsigned int*)l, 16, 0, 0);
}

// ---------------- codebook prep ----------------
__global__ __launch_bounds__(256) void k_prep(const float* __restrict__ emb,
                                              char* __restrict__ Eb,
                                              float* __restrict__ cn,
                                              float* __restrict__ loss) {
    const int t = threadIdx.x;
    const int row = (blockIdx.x << 4) + (t >> 4), c = t & 15;
    const float4* ep = (const float4*)(emb + ((size_t)row << 7) + (c << 3));
    float4 e0 = ep[0], e1 = ep[1];
    float s = e0.x*e0.x + e0.y*e0.y + e0.z*e0.z + e0.w*e0.w
            + e1.x*e1.x + e1.y*e1.y + e1.z*e1.z + e1.w*e1.w;
#pragma unroll
    for (int m = 1; m < 16; m <<= 1) s += __shfl_xor(s, m);
    if (c == 0) cn[row] = s;
    uint2 v;
    v.x = cvt4_fp8(512.f*e0.x, 512.f*e0.y, 512.f*e0.z, 512.f*e0.w);
    v.y = cvt4_fp8(512.f*e1.x, 512.f*e1.y, 512.f*e1.z, 512.f*e1.w);
    *(uint2*)(Eb + row * 128 + ((c * 8) ^ ((row & 7) << 4))) = v;
    if (blockIdx.x == 0 && t == 0) loss[0] = 0.f;
}

// ---------------- fused: E-resident scoring + gather ----------------
// LDS: E @0 (128K) | win @131072 (512B) | rs @131584 (32B) = 131616 B.
__global__ __launch_bounds__(512, 1) void k_fused(const float* __restrict__ lat,
                                                  const float* __restrict__ emb,
                                                  const char* __restrict__ Eb,
                                                  const float* __restrict__ cn,
                                                  float* __restrict__ outq,
                                                  float* __restrict__ loss) {
    __shared__ char lds[131616];
    char*  ldsE = lds;                       // fp8 swz [1024][128]
    int*   win  = (int*)  (lds + 131072);    // [128]
    float* rs   = (float*)(lds + 131584);    // [8]

    const int t = threadIdx.x, bm = blockIdx.x;     // 256 blocks
    const int lane = t & 63, w = t >> 6;            // 8 waves
    const int l15 = lane & 15, lg = lane >> 4;
    const int b = bm >> 3, hw0 = (bm & 7) << 7;     // 128 rows, line-aligned

    // ---- stage full E image (128 KB), latency hides under A-frag build ----
#pragma unroll
    for (int i = 0; i < 16; ++i) {
        int base = i * 8192 + (w << 10);            // wave-uniform byte base
        gload_lds16(Eb + base + lane * 16, ldsE + base);
    }

    // ---- A-frags direct from lat (regs), row-norm partial in same pass ----
    const float* lp = lat + ((size_t)b << 17) + hw0 + (w << 4) + l15;
    float xv[4][8];
#pragma unroll
    for (int ks = 0; ks < 4; ++ks)
#pragma unroll
        for (int j = 0; j < 8; ++j)
            xv[ks][j] = lp[(size_t)(ks * 32 + lg * 8 + j) << 10];

    float rn = 0.f;
    long av[4];
#pragma unroll
    for (int ks = 0; ks < 4; ++ks) {
#pragma unroll
        for (int j = 0; j < 8; ++j) rn = fmaf(xv[ks][j], xv[ks][j], rn);
        unsigned lo = cvt4_fp8(xv[ks][0], xv[ks][1], xv[ks][2], xv[ks][3]);
        unsigned hi = cvt4_fp8(xv[ks][4], xv[ks][5], xv[ks][6], xv[ks][7]);
        av[ks] = (long)(((unsigned long long)hi << 32) | lo);
    }
    __syncthreads();                 // E image resident (vmcnt drained)

    // ---- phase B: barrier-free sweep of all 1024 codes from LDS ----
    float run_s[4]; int run_i[4];
#pragma unroll
    for (int r = 0; r < 4; ++r) { run_s[r] = 3.0e38f; run_i[r] = 0; }

    for (int ct = 0; ct < 8; ++ct) {
        float cnv[8];
#pragma unroll
        for (int c = 0; c < 8; ++c) cnv[c] = cn[(ct << 7) + (c << 4) + l15];

        f32x4 acc[8];
#pragma unroll
        for (int c = 0; c < 8; ++c) acc[c] = (f32x4){0.f, 0.f, 0.f, 0.f};
#pragma unroll
        for (int ks = 0; ks < 4; ++ks) {
            long bv[8];
#pragma unroll
            for (int c = 0; c < 8; ++c) {
                int rr = (ct << 7) + (c << 4) + l15;
                bv[c] = *(const long*)(ldsE + rr * 128 +
                         ((ks * 32 + lg * 8) ^ ((rr & 7) << 4)));
            }
#pragma unroll
            for (int c = 0; c < 8; ++c)
                acc[c] = __builtin_amdgcn_mfma_f32_16x16x32_fp8_fp8(av[ks], bv[c], acc[c], 0, 0, 0);
        }
#pragma unroll
        for (int c = 0; c < 8; ++c) {
            int kg = (ct << 7) + (c << 4) + l15;
#pragma unroll
            for (int r = 0; r < 4; ++r) {
                float s = fmaf(NEG2_INV_LAMBDA, acc[c][r], cnv[c]);
                if (s < run_s[r]) { run_s[r] = s; run_i[r] = kg; }
            }
        }
    }

    // ---- in-wave merge: butterfly over 16 cols; win + loss partials ----
    float bs = 0.f;
#pragma unroll
    for (int r = 0; r < 4; ++r) {
        float s = run_s[r]; int bi = run_i[r];
#pragma unroll
        for (int mask = 1; mask < 16; mask <<= 1) {
            float os = __shfl_xor(s, mask);
            int   oi = __shfl_xor(bi, mask);
            if (os < s || (os == s && oi < bi)) { s = os; bi = oi; }
        }
        if (l15 == 0) {
            win[(w << 4) + (lg << 2) + r] = bi;    // C row = lg*4 + reg
            bs += s;
        }
    }
    {
        float v = ((l15 == 0) ? bs : 0.f) + rn;
#pragma unroll
        for (int m = 1; m < 64; m <<= 1) v += __shfl_xor(v, m);
        if (lane == 0) rs[w] = v;
    }
    __syncthreads();
    if (t == 0) {
        float v = rs[0] + rs[1] + rs[2] + rs[3] + rs[4] + rs[5] + rs[6] + rs[7];
        atomicAdd(loss, v * LOSS_SCALE);
    }

    // ---- gather q = emb[k*] fp32, store [B,D,H,W] coalesced ----
    {
        const int rowl = t & 127, dg = t >> 7;      // 4 dgrps x 32 d
        const int bi = win[rowl];
        const float4* eg = (const float4*)(emb + ((size_t)bi << 7) + (dg << 5));
        float* ob = outq + ((size_t)b << 17) + ((size_t)(dg << 5) << 10) + hw0 + rowl;
#pragma unroll
        for (int jj = 0; jj < 8; ++jj) {
            float4 v = eg[jj];
            ob[(size_t)(jj * 4 + 0) << 10] = v.x;
            ob[(size_t)(jj * 4 + 1) << 10] = v.y;
            ob[(size_t)(jj * 4 + 2) << 10] = v.z;
            ob[(size_t)(jj * 4 + 3) << 10] = v.w;
        }
    }
}

extern "C" void kernel_launch(void* const* d_in, const int* in_sizes, int n_in,
                              void* d_out, int out_size, void* d_ws, size_t ws_size,
                              hipStream_t stream) {
    const float* lat = (const float*)d_in[0];   // [32,128,32,32]
    const float* emb = (const float*)d_in[1];   // [1024,128]
    float* out = (float*)d_out;                 // q (4194304) + vq_loss (1)
    char* ws = (char*)d_ws;
    char*  E    = ws + WS_E;
    float* cn   = (float*)(ws + WS_C);
    float* loss = out + 4194304;

    k_prep <<<64,  256, 0, stream>>>(emb, E, cn, loss);
    k_fused<<<256, 512, 0, stream>>>(lat, emb, E, cn, out, loss);
}